// Round 1
// baseline (26.178 us; speedup 1.0000x reference)
//
#include <hip/hip_runtime.h>

// Problem constants (match reference)
#define BATCH 16
#define CHN   3
#define IMG_H 1024
#define IMG_W 2048
#define NPATCH 80
#define PSZ   16   // patch is 16x16

__global__ __launch_bounds__(256)
void TangentPlane_41644002902481_kernel(const float* __restrict__ x,
                                        const float* __restrict__ coords,
                                        float* __restrict__ out) {
    const int bid = blockIdx.x;        // (b*NPATCH + patch)*CHN + c
    const int tid = threadIdx.x;       // i*16 + j within the 16x16 patch

    const int c     = bid % CHN;
    const int t     = bid / CHN;
    const int patch = t % NPATCH;
    const int b     = t / NPATCH;

    // coords[patch, i, j, 0:2] — coalesced float2 load
    const float2 uv = reinterpret_cast<const float2*>(coords)[patch * (PSZ * PSZ) + tid];
    const float u = uv.x;
    const float v = uv.y;

    const float x0f = floorf(u);
    const float y0f = floorf(v);
    const float wu = u - x0f;
    const float wv = v - y0f;

    int x0 = (int)x0f;
    int y0 = (int)y0f;
    // wrap in x (reference: mod), clamp in y (reference: clip)
    x0 = ((x0 % IMG_W) + IMG_W) % IMG_W;
    int x1 = x0 + 1; if (x1 >= IMG_W) x1 = 0;
    y0 = min(max(y0, 0), IMG_H - 1);
    const int y1 = min(y0 + 1, IMG_H - 1);

    const float* __restrict__ plane =
        x + (size_t)(b * CHN + c) * (size_t)(IMG_H * IMG_W);

    const float g00 = plane[(size_t)y0 * IMG_W + x0];
    const float g01 = plane[(size_t)y0 * IMG_W + x1];
    const float g10 = plane[(size_t)y1 * IMG_W + x0];
    const float g11 = plane[(size_t)y1 * IMG_W + x1];

    const float o = g00 * (1.0f - wu) * (1.0f - wv)
                  + g01 * wu * (1.0f - wv)
                  + g10 * (1.0f - wu) * wv
                  + g11 * wu * wv;

    // out[b, patch, c*256 + i*16 + j]
    out[(size_t)bid * (PSZ * PSZ) + tid] = o;
}

extern "C" void kernel_launch(void* const* d_in, const int* in_sizes, int n_in,
                              void* d_out, int out_size, void* d_ws, size_t ws_size,
                              hipStream_t stream) {
    const float* x      = (const float*)d_in[0];   // (16,3,1024,2048) fp32
    const float* coords = (const float*)d_in[1];   // (80,16,16,2) fp32
    float* out          = (float*)d_out;           // (16,80,768) fp32

    const int grid = BATCH * NPATCH * CHN;         // 3840 blocks
    TangentPlane_41644002902481_kernel<<<grid, 256, 0, stream>>>(x, coords, out);
}